// Round 8
// baseline (171.720 us; speedup 1.0000x reference)
//
#include <hip/hip_runtime.h>

// Problem: B=16, C=4, H=W=512. input [B,C,H,W] f32; target [B,C+1,H,W] f32,
// last channel a {0,1} mask. Output scalar:
//   (1/B) * sum_b [ cnt_b>0 ? sum_{c,hw} mask*(in-tg)^2 / (C*cnt_b) : 0 ]
//
// History: R1/R3/R5 (9 streams/block) pinned at ~60 us / 2.65 TB/s. R7
// (3 streams/block, XCD-swizzled mask reuse, nontemporal in/tg): ~47 us /
// ~4.1 TB/s. R2: no __threadfence. R4: no DMA-staging. R8: same per-wave
// shape, 2x blocks (2048) -> 32 waves/CU chip-wide MLP test.

#define BATCH 16
#define CHAN 4
#define HWPIX (512 * 512)                 // 262144 pixels per plane
#define CHUNK_PX 8192                     // pixels per chunk
#define CPB (HWPIX / CHUNK_PX)            // 32 chunks per plane
#define UNITS (BATCH * CPB)               // 512 (b,k) units
#define THREADS 256
#define TOTAL_BLOCKS (UNITS * CHAN)       // 2048 blocks
#define G4 (CHUNK_PX / 4)                 // 2048 float4 per chunk-plane
#define ITERS (G4 / THREADS)              // 8 iterations per thread

typedef float vf4 __attribute__((ext_vector_type(4)));

__global__ __launch_bounds__(THREADS) void masked_mse_partial(
    const float* __restrict__ input,
    const float* __restrict__ target,
    float* __restrict__ ws) {
    // blockIdx swizzle: idx = q*32 + c*8 + r. All four c-blocks of unit
    // u=(q,r) are congruent mod 8 -> same XCD, dispatched within a 32-block
    // window -> mask chunk L2-hits on 3 of 4 reads.
    const int bid = blockIdx.x;
    const int r   = bid & 7;
    const int c   = (bid >> 3) & 3;
    const int q   = bid >> 5;
    const int u   = q * 8 + r;            // [0, 512)
    const int b   = u >> 5;               // u / CPB
    const int k   = u & (CPB - 1);

    const vf4* ip = (const vf4*)(input  + ((size_t)b * CHAN + c) * HWPIX
                                        + (size_t)k * CHUNK_PX);
    const vf4* tp = (const vf4*)(target + ((size_t)b * (CHAN + 1) + c) * HWPIX
                                        + (size_t)k * CHUNK_PX);
    const vf4* mp = (const vf4*)(target + ((size_t)b * (CHAN + 1) + CHAN) * HWPIX
                                        + (size_t)k * CHUNK_PX);

    float s = 0.f, cnt = 0.f;

    // 12 grouped loads (4 iters x 3 streams) before any use.
#pragma unroll
    for (int it = 0; it < ITERS; it += 4) {
        const int g0 = it * THREADS + threadIdx.x;
        vf4 a0 = __builtin_nontemporal_load(&ip[g0]);
        vf4 a1 = __builtin_nontemporal_load(&ip[g0 + THREADS]);
        vf4 a2 = __builtin_nontemporal_load(&ip[g0 + 2 * THREADS]);
        vf4 a3 = __builtin_nontemporal_load(&ip[g0 + 3 * THREADS]);
        vf4 t0 = __builtin_nontemporal_load(&tp[g0]);
        vf4 t1 = __builtin_nontemporal_load(&tp[g0 + THREADS]);
        vf4 t2 = __builtin_nontemporal_load(&tp[g0 + 2 * THREADS]);
        vf4 t3 = __builtin_nontemporal_load(&tp[g0 + 3 * THREADS]);
        vf4 m0 = mp[g0];
        vf4 m1 = mp[g0 + THREADS];
        vf4 m2 = mp[g0 + 2 * THREADS];
        vf4 m3 = mp[g0 + 3 * THREADS];

        vf4 d0 = a0 - t0, d1 = a1 - t1, d2 = a2 - t2, d3 = a3 - t3;
        vf4 acc = d0 * d0 * m0 + d1 * d1 * m1 + d2 * d2 * m2 + d3 * d3 * m3;
        s += acc.x + acc.y + acc.z + acc.w;

        if (c == 0) {   // wave-uniform: count mask once per (b,k) unit
            vf4 mc = m0 + m1 + m2 + m3;
            cnt += mc.x + mc.y + mc.z + mc.w;
        }
    }

    // wave-64 shuffle reduction
#pragma unroll
    for (int off = 32; off > 0; off >>= 1) {
        s   += __shfl_down(s, off, 64);
        cnt += __shfl_down(cnt, off, 64);
    }

    __shared__ float ss[THREADS / 64];
    __shared__ float sc[THREADS / 64];
    const int lane = threadIdx.x & 63;
    const int wid  = threadIdx.x >> 6;
    if (lane == 0) { ss[wid] = s; sc[wid] = cnt; }
    __syncthreads();

    if (threadIdx.x == 0) {
        float S = 0.f, Cn = 0.f;
#pragma unroll
        for (int w = 0; w < THREADS / 64; ++w) { S += ss[w]; Cn += sc[w]; }
        atomicAdd(&ws[2 * b],     S);
        if (c == 0) atomicAdd(&ws[2 * b + 1], Cn);
    }
}

__global__ void masked_mse_final(const float* __restrict__ ws,
                                 float* __restrict__ out) {
    if (threadIdx.x == 0 && blockIdx.x == 0) {
        float acc = 0.f;
#pragma unroll
        for (int b = 0; b < BATCH; ++b) {
            float s  = ws[2 * b];
            float cb = ws[2 * b + 1] * (float)CHAN;   // C * #masked pixels
            acc += (cb > 0.f) ? (s / cb) : 0.f;
        }
        out[0] = acc / (float)BATCH;
    }
}

extern "C" void kernel_launch(void* const* d_in, const int* in_sizes, int n_in,
                              void* d_out, int out_size, void* d_ws, size_t ws_size,
                              hipStream_t stream) {
    const float* input  = (const float*)d_in[0];
    const float* target = (const float*)d_in[1];
    float* out = (float*)d_out;
    float* ws  = (float*)d_ws;

    // zero per-batch {sum, count} accumulators (d_ws is re-poisoned to 0xAA)
    (void)hipMemsetAsync(ws, 0, 2 * BATCH * sizeof(float), stream);

    masked_mse_partial<<<dim3(TOTAL_BLOCKS), dim3(THREADS), 0, stream>>>(
        input, target, ws);
    masked_mse_final<<<1, 64, 0, stream>>>(ws, out);
}

// Round 9
// 170.274 us; speedup vs baseline: 1.0085x; 1.0085x over previous
//
#include <hip/hip_runtime.h>

// Problem: B=16, C=4, H=W=512. input [B,C,H,W] f32; target [B,C+1,H,W] f32,
// last channel a {0,1} mask. Output scalar:
//   (1/B) * sum_b [ cnt_b>0 ? sum_{c,hw} mask*(in-tg)^2 / (C*cnt_b) : 0 ]
//
// History: R1/R3/R5 (9 concurrent streams/wave) ~60 us / 2.65 TB/s.
// R7 (3 streams/wave) ~47 us / 4.1 TB/s demand. R8 (2x blocks) neutral ->
// wave count not the limiter; access shape is. R2: no __threadfence.
// R4: no DMA staging. R9: mask chunk in registers (read once, no 4x
// re-read), channel loop sequential -> inner loop is a 2-stream copy-like
// walk. unroll 1 pins the 2-stream shape.

#define BATCH 16
#define CHAN 4
#define HWPIX (512 * 512)                 // 262144 pixels per plane
#define CHUNK_PX 4096                     // pixels per (b,k) unit
#define CPB (HWPIX / CHUNK_PX)            // 64 chunks per plane
#define THREADS 256
#define TOTAL_BLOCKS (BATCH * CPB)        // 1024 blocks
#define PER (CHUNK_PX / 4 / THREADS)      // 4 vf4 per thread per plane

typedef float vf4 __attribute__((ext_vector_type(4)));

__global__ __launch_bounds__(THREADS) void masked_mse_partial(
    const float* __restrict__ input,
    const float* __restrict__ target,
    float* __restrict__ ws) {
    const int u = blockIdx.x;             // consecutive blocks -> consecutive chunks
    const int b = u / CPB;
    const int k = u % CPB;

    const size_t chunk_off = (size_t)k * CHUNK_PX;
    const vf4* mp = (const vf4*)(target + ((size_t)b * (CHAN + 1) + CHAN) * HWPIX
                                        + chunk_off);

    // Stage the mask chunk in registers: 4 vf4 = 16 VGPRs, read exactly once.
    vf4 m[PER];
#pragma unroll
    for (int j = 0; j < PER; ++j)
        m[j] = __builtin_nontemporal_load(&mp[threadIdx.x + j * THREADS]);

    float cnt = 0.f;
#pragma unroll
    for (int j = 0; j < PER; ++j) cnt += m[j].x + m[j].y + m[j].z + m[j].w;

    float s = 0.f;

    // Sequential channel loop: at any instant the wave walks exactly 2
    // streams (in + tg), 8 grouped loads before use. Do NOT unroll -- that
    // would recreate the slow 9-stream interleave.
#pragma unroll 1
    for (int c = 0; c < CHAN; ++c) {
        const vf4* ip = (const vf4*)(input  + ((size_t)b * CHAN + c) * HWPIX
                                            + chunk_off);
        const vf4* tp = (const vf4*)(target + ((size_t)b * (CHAN + 1) + c) * HWPIX
                                            + chunk_off);
        vf4 a[PER], t[PER];
#pragma unroll
        for (int j = 0; j < PER; ++j)
            a[j] = __builtin_nontemporal_load(&ip[threadIdx.x + j * THREADS]);
#pragma unroll
        for (int j = 0; j < PER; ++j)
            t[j] = __builtin_nontemporal_load(&tp[threadIdx.x + j * THREADS]);
#pragma unroll
        for (int j = 0; j < PER; ++j) {
            vf4 d = a[j] - t[j];
            vf4 p = d * d * m[j];
            s += p.x + p.y + p.z + p.w;
        }
    }

    // wave-64 shuffle reduction
#pragma unroll
    for (int off = 32; off > 0; off >>= 1) {
        s   += __shfl_down(s, off, 64);
        cnt += __shfl_down(cnt, off, 64);
    }

    __shared__ float ss[THREADS / 64];
    __shared__ float sc[THREADS / 64];
    const int lane = threadIdx.x & 63;
    const int wid  = threadIdx.x >> 6;
    if (lane == 0) { ss[wid] = s; sc[wid] = cnt; }
    __syncthreads();

    if (threadIdx.x == 0) {
        float S = 0.f, Cn = 0.f;
#pragma unroll
        for (int w = 0; w < THREADS / 64; ++w) { S += ss[w]; Cn += sc[w]; }
        atomicAdd(&ws[2 * b],     S);
        atomicAdd(&ws[2 * b + 1], Cn);
    }
}

__global__ void masked_mse_final(const float* __restrict__ ws,
                                 float* __restrict__ out) {
    if (threadIdx.x == 0 && blockIdx.x == 0) {
        float acc = 0.f;
#pragma unroll
        for (int b = 0; b < BATCH; ++b) {
            float s  = ws[2 * b];
            float cb = ws[2 * b + 1] * (float)CHAN;   // C * #masked pixels
            acc += (cb > 0.f) ? (s / cb) : 0.f;
        }
        out[0] = acc / (float)BATCH;
    }
}

extern "C" void kernel_launch(void* const* d_in, const int* in_sizes, int n_in,
                              void* d_out, int out_size, void* d_ws, size_t ws_size,
                              hipStream_t stream) {
    const float* input  = (const float*)d_in[0];
    const float* target = (const float*)d_in[1];
    float* out = (float*)d_out;
    float* ws  = (float*)d_ws;

    // zero per-batch {sum, count} accumulators (d_ws is re-poisoned to 0xAA)
    (void)hipMemsetAsync(ws, 0, 2 * BATCH * sizeof(float), stream);

    masked_mse_partial<<<dim3(TOTAL_BLOCKS), dim3(THREADS), 0, stream>>>(
        input, target, ws);
    masked_mse_final<<<1, 64, 0, stream>>>(ws, out);
}

// Round 10
// 167.266 us; speedup vs baseline: 1.0266x; 1.0180x over previous
//
#include <hip/hip_runtime.h>

// Problem: B=16, C=4, H=W=512. input [B,C,H,W] f32; target [B,C+1,H,W] f32,
// last channel a {0,1} mask. Output scalar:
//   (1/B) * sum_b [ cnt_b>0 ? sum_{c,hw} mask*(in-tg)^2 / (C*cnt_b) : 0 ]
//
// History: R1/R3/R5 (9 concurrent streams/wave) ~60 us / 2.65 TB/s.
// R7 (3 streams/wave, XCD-swizzled mask L2 reuse, nt in/tg) ~47 us — best.
// R8 (2x blocks) neutral -> wave count saturated. R9 (mask-in-regs,
// serialized channels) slower -> drain count / MLP depth matters, byte
// count doesn't. R2: no __threadfence. R4: no DMA staging.
// R10: R7 structure, load groups deepened 12 -> 24 (8 iters x 3 streams).

#define BATCH 16
#define CHAN 4
#define HWPIX (512 * 512)                 // 262144 pixels per plane
#define CHUNK_PX 16384                    // pixels per chunk
#define CPB (HWPIX / CHUNK_PX)            // 16 chunks per plane
#define UNITS (BATCH * CPB)               // 256 (b,k) units
#define THREADS 256
#define TOTAL_BLOCKS (UNITS * CHAN)       // 1024 blocks
#define G4 (CHUNK_PX / 4)                 // 4096 float4 per chunk-plane
#define ITERS (G4 / THREADS)              // 16 iterations per thread
#define DEPTH 8                           // iters per load group (24 loads)

typedef float vf4 __attribute__((ext_vector_type(4)));

__global__ __launch_bounds__(THREADS) void masked_mse_partial(
    const float* __restrict__ input,
    const float* __restrict__ target,
    float* __restrict__ ws) {
    // blockIdx swizzle: idx = q*32 + c*8 + r. All four c-blocks of unit
    // u=(q,r) are congruent mod 8 -> same XCD, dispatched within a 32-block
    // window -> mask chunk L2-hits on 3 of 4 reads.
    const int bid = blockIdx.x;
    const int r   = bid & 7;
    const int c   = (bid >> 3) & 3;
    const int q   = bid >> 5;
    const int u   = q * 8 + r;            // [0, 256)
    const int b   = u >> 4;               // u / CPB
    const int k   = u & (CPB - 1);

    const vf4* ip = (const vf4*)(input  + ((size_t)b * CHAN + c) * HWPIX
                                        + (size_t)k * CHUNK_PX);
    const vf4* tp = (const vf4*)(target + ((size_t)b * (CHAN + 1) + c) * HWPIX
                                        + (size_t)k * CHUNK_PX);
    const vf4* mp = (const vf4*)(target + ((size_t)b * (CHAN + 1) + CHAN) * HWPIX
                                        + (size_t)k * CHUNK_PX);

    float s = 0.f, cnt = 0.f;

    // 24 grouped loads (8 iters x 3 streams) before any use -> ~96 data
    // VGPRs live, half the wave-drain stalls of the 12-load version.
#pragma unroll 1
    for (int it = 0; it < ITERS; it += DEPTH) {
        const int g0 = it * THREADS + threadIdx.x;
        vf4 a[DEPTH], t[DEPTH], m[DEPTH];
#pragma unroll
        for (int j = 0; j < DEPTH; ++j)
            a[j] = __builtin_nontemporal_load(&ip[g0 + j * THREADS]);
#pragma unroll
        for (int j = 0; j < DEPTH; ++j)
            t[j] = __builtin_nontemporal_load(&tp[g0 + j * THREADS]);
#pragma unroll
        for (int j = 0; j < DEPTH; ++j)
            m[j] = mp[g0 + j * THREADS];

#pragma unroll
        for (int j = 0; j < DEPTH; ++j) {
            vf4 d = a[j] - t[j];
            vf4 p = d * d * m[j];
            s += p.x + p.y + p.z + p.w;
        }
        if (c == 0) {   // wave-uniform: count mask once per (b,k) unit
#pragma unroll
            for (int j = 0; j < DEPTH; ++j)
                cnt += m[j].x + m[j].y + m[j].z + m[j].w;
        }
    }

    // wave-64 shuffle reduction
#pragma unroll
    for (int off = 32; off > 0; off >>= 1) {
        s   += __shfl_down(s, off, 64);
        cnt += __shfl_down(cnt, off, 64);
    }

    __shared__ float ss[THREADS / 64];
    __shared__ float sc[THREADS / 64];
    const int lane = threadIdx.x & 63;
    const int wid  = threadIdx.x >> 6;
    if (lane == 0) { ss[wid] = s; sc[wid] = cnt; }
    __syncthreads();

    if (threadIdx.x == 0) {
        float S = 0.f, Cn = 0.f;
#pragma unroll
        for (int w = 0; w < THREADS / 64; ++w) { S += ss[w]; Cn += sc[w]; }
        atomicAdd(&ws[2 * b],     S);
        if (c == 0) atomicAdd(&ws[2 * b + 1], Cn);
    }
}

__global__ void masked_mse_final(const float* __restrict__ ws,
                                 float* __restrict__ out) {
    if (threadIdx.x == 0 && blockIdx.x == 0) {
        float acc = 0.f;
#pragma unroll
        for (int b = 0; b < BATCH; ++b) {
            float s  = ws[2 * b];
            float cb = ws[2 * b + 1] * (float)CHAN;   // C * #masked pixels
            acc += (cb > 0.f) ? (s / cb) : 0.f;
        }
        out[0] = acc / (float)BATCH;
    }
}

extern "C" void kernel_launch(void* const* d_in, const int* in_sizes, int n_in,
                              void* d_out, int out_size, void* d_ws, size_t ws_size,
                              hipStream_t stream) {
    const float* input  = (const float*)d_in[0];
    const float* target = (const float*)d_in[1];
    float* out = (float*)d_out;
    float* ws  = (float*)d_ws;

    // zero per-batch {sum, count} accumulators (d_ws is re-poisoned to 0xAA)
    (void)hipMemsetAsync(ws, 0, 2 * BATCH * sizeof(float), stream);

    masked_mse_partial<<<dim3(TOTAL_BLOCKS), dim3(THREADS), 0, stream>>>(
        input, target, ws);
    masked_mse_final<<<1, 64, 0, stream>>>(ws, out);
}